// Round 14
// baseline (355.172 us; speedup 1.0000x reference)
//
#include <hip/hip_runtime.h>
#include <hip/hip_bf16.h>
#include <stdint.h>

// Problem constants
#define TLEN 4096
#define DMm  2048
#define DD   4096
#define DGg  512
#define BT   8192          // B*T
#define DW   16384         // D*W

typedef __attribute__((ext_vector_type(8))) short bf16x8;
typedef __attribute__((ext_vector_type(4))) float f32x4;

__device__ __forceinline__ unsigned short f2bf(float f) {
    union { float f; unsigned u; } c; c.f = f;
    unsigned u = c.u;
    unsigned r = (u + 0x7FFFu + ((u >> 16) & 1u)) >> 16;   // RNE
    return (unsigned short)r;
}

// ---------------- fused cast f32 -> bf16 for gen|w1|w2 (contiguous in ws) ----
#define NB1 (BT * DMm / 4)
#define NB2 (DGg * DMm / 4)
#define NB3 (DW * DGg / 4)
__global__ void cast_all_kernel(const float* __restrict__ g,
                                const float* __restrict__ w1,
                                const float* __restrict__ w2,
                                unsigned short* __restrict__ o) {
    int i = blockIdx.x * blockDim.x + threadIdx.x;
    if (i >= NB1 + NB2 + NB3) return;
    const float* src; int j = i;
    if (j < NB1) { src = g; }
    else if (j < NB1 + NB2) { src = w1; j -= NB1; }
    else { src = w2; j -= NB1 + NB2; }
    float4 v = reinterpret_cast<const float4*>(src)[j];
    ushort4 u;
    u.x = f2bf(v.x); u.y = f2bf(v.y); u.z = f2bf(v.z); u.w = f2bf(v.w);
    reinterpret_cast<ushort4*>(o)[i] = u;
}

#define GLDS16(gp, lp)                                                         \
    __builtin_amdgcn_global_load_lds(                                          \
        (__attribute__((address_space(1))) const void*)(gp),                   \
        (__attribute__((address_space(3))) void*)(lp), 16, 0, 0)

#define VMCNT(n) asm volatile("s_waitcnt vmcnt(" #n ")" ::: "memory")
#define SBAR()   __builtin_amdgcn_s_barrier()
#define SCHED0() __builtin_amdgcn_sched_barrier(0)

// ---------------- GEMM1: h = silu(gen @ w1^T), bf16 out (unchanged) ----------
__global__ __launch_bounds__(256) void gemm1_silu_kernel(
    const unsigned short* __restrict__ A,
    const unsigned short* __restrict__ Bm,
    unsigned short* __restrict__ H)
{
    __shared__ short smA[128 * 32];
    __shared__ short smB[128 * 32];
    const int m0   = blockIdx.y * 128;
    const int n0   = blockIdx.x * 128;
    const int lane = threadIdx.x & 63;
    const int wave = threadIdx.x >> 6;
    const int wm   = wave >> 1, wn = wave & 1;

    const int c0 = wave * 64 + lane;
    const int c1 = c0 + 256;
    const int rA0 = m0 + (c0 >> 2), rA1 = m0 + (c1 >> 2);
    const int rB0 = n0 + (c0 >> 2), rB1 = n0 + (c1 >> 2);
    const int ko0 = (c0 & 3) * 8,  ko1 = (c1 & 3) * 8;

    f32x4 acc[4][4] = {};

    for (int k0 = 0; k0 < DMm; k0 += 32) {
        GLDS16(A  + (size_t)rA0 * DMm + k0 + ko0, smA + wave * 512);
        GLDS16(A  + (size_t)rA1 * DMm + k0 + ko1, smA + 2048 + wave * 512);
        GLDS16(Bm + (size_t)rB0 * DMm + k0 + ko0, smB + wave * 512);
        GLDS16(Bm + (size_t)rB1 * DMm + k0 + ko1, smB + 2048 + wave * 512);
        __syncthreads();

        const int la = lane & 15, ko = (lane >> 4) * 8;
        bf16x8 af[4], bfr[4];
#pragma unroll
        for (int mm = 0; mm < 4; ++mm)
            af[mm] = *reinterpret_cast<const bf16x8*>(&smA[(wm * 64 + mm * 16 + la) * 32 + ko]);
#pragma unroll
        for (int nn = 0; nn < 4; ++nn)
            bfr[nn] = *reinterpret_cast<const bf16x8*>(&smB[(wn * 64 + nn * 16 + la) * 32 + ko]);
#pragma unroll
        for (int mm = 0; mm < 4; ++mm)
#pragma unroll
            for (int nn = 0; nn < 4; ++nn)
                acc[mm][nn] = __builtin_amdgcn_mfma_f32_16x16x32_bf16(
                    af[mm], bfr[nn], acc[mm][nn], 0, 0, 0);
        __syncthreads();
    }

#pragma unroll
    for (int mm = 0; mm < 4; ++mm) {
        int rowB = m0 + wm * 64 + mm * 16 + (lane >> 4) * 4;
#pragma unroll
        for (int nn = 0; nn < 4; ++nn) {
            int colG = n0 + wn * 64 + nn * 16 + (lane & 15);
#pragma unroll
            for (int j = 0; j < 4; ++j) {
                float v = acc[mm][nn][j];
                float s = v / (1.0f + __expf(-v));
                H[(size_t)(rowB + j) * DGg + colG] = f2bf(s);
            }
        }
    }
}

// ===== GEMM2 fused: 256n x 128t, A(W2) DIRECT global->VGPR, B(H) LDS ring-4 =====
// D[n][t] = sum_k W2b[n][k] * Hb[t][k]   (n = 4d+w; conv taps w = acc reg idx j)
// 8 waves (wm 0..3 n-quarters x wn 0..1 t-halves), wave 64n x 64t, 2 blk/CU.
// A fragments are loaded DIRECTLY from global (L2-hot W2 panel, per-XCD
// disjoint 2MB): lanes {la,la+16,la+32,la+48} cover one 64B line -> fully
// line-efficient.  Removes A from LDS: reads/wave/region 8 -> 4 b128, and A
// staging writes vanish -> LDS pipe no longer binding (MFMA floor 66us).
// A ping-pong 2 sets, stage-1-ahead (region r issues A(r+1) into set (r+1)&1,
// MFMA uses set r&1; compiler auto-vmcnt covers the reg dependency).
// B ring-4 (1 gload_lds/thread/tile), stage-3-ahead.  Region r issue order:
// [A(r+1) x4, B(r+3) x1] -> FIFO ledger: explicit VMCNT(6) (r<=12) / (5) at
// r13 / (4) at r14 before each SBAR certifies B(r+1) for ALL waves.
// LDS: B[4 par][128 rows][64B] @0 (32K); post-loop overlay X f32[131][68] @0,
// Y f32[128][68] @35632 (70448 peak) -> 2 blocks/CU.
#define XSTR2 68

__global__ __launch_bounds__(512, 4) void gemm2_conv_silu_kernel(
    const unsigned short* __restrict__ Hb,
    const unsigned short* __restrict__ W2b,
    const float* __restrict__ b2,
    const float* __restrict__ x,
    float* __restrict__ out)
{
    __shared__ __attribute__((aligned(16))) char lds[70448];
    const int tid  = threadIdx.x;
    const int lane = tid & 63, wave = tid >> 6;
    const int wm   = wave >> 1, wn = wave & 1;
    const int la   = lane & 15, hi = lane >> 4;

    // XCD-aware swizzle (4096 blocks, %8==0 -> bijective); t fast within XCD
    // -> each XCD touches a disjoint 2MB set of W2 panels (L2-resident).
    int bid = blockIdx.x;
    int swz = (bid & 7) * 512 + (bid >> 3);
    const int n0 = (swz >> 6) * 256;   // 64 n-tiles
    const int t0 = (swz & 63) * 128;   // 64 t-tiles
    const int d0 = n0 >> 2;

    const int srow = lane >> 2;                               // 0..15
    const int scol = ((lane & 3) ^ ((srow >> 1) & 3)) * 8;    // pre-swizzled src col

    auto stageB = [&](int tk, int p) {   // 1 load/thread: 8KB tile (128 rows)
        int row = wave * 16 + srow;                           // 0..127
        GLDS16(Hb + (size_t)(t0 + row) * DGg + tk * 32 + scol,
               lds + p * 8192 + wave * 1024);
    };

    // A-direct: lane reads 16B at W2[n0 + wm*64 + m*16 + la][tk*32 + hi*8]
    const unsigned short* aBase = W2b + (size_t)(n0 + wm * 64 + la) * DGg + hi * 8;
    auto loadA = [&](bf16x8 (&dst)[4], int tk) {
#pragma unroll
        for (int m = 0; m < 4; ++m)
            dst[m] = *reinterpret_cast<const bf16x8*>(aBase + (size_t)m * 16 * DGg + tk * 32);
    };

    f32x4 acc[4][4] = {};
    const int slotb = (hi ^ ((la >> 1) & 3)) * 16;   // swizzled 16B slot
    const int bOff  = (wn * 64 + la) * 64 + slotb;

    bf16x8 aF0[4], aF1[4];

    // Region body: bF reads (LDS) + A(r+1) issue + B(r+3) stage, MFMA(setCur).
    auto body = [&](bf16x8 (&AC)[4], bf16x8 (&AN)[4], int p, int tkA, bool doA,
                    int tkB, bool doB) {
        bf16x8 bF[4];
        const char* bB = lds + p * 8192 + bOff;
#pragma unroll
        for (int nr = 0; nr < 4; ++nr)
            bF[nr] = *reinterpret_cast<const bf16x8*>(bB + nr * 1024);
        if (doA) loadA(AN, tkA);
        if (doB) stageB(tkB, tkB & 3);
        SCHED0();   // pin reads+issues above the MFMA cluster
        __builtin_amdgcn_s_setprio(1);
#pragma unroll
        for (int m = 0; m < 4; ++m)
#pragma unroll
            for (int nr = 0; nr < 4; ++nr)
                acc[m][nr] = __builtin_amdgcn_mfma_f32_16x16x32_bf16(
                    AC[m], bF[nr], acc[m][nr], 0, 0, 0);
        __builtin_amdgcn_s_setprio(0);
        SCHED0();
    };

    // ---- prologue: A0 direct; stage B tiles 0,1,2 ----
    loadA(aF0, 0);
    stageB(0, 0); stageB(1, 1); stageB(2, 2);
    VMCNT(2);     // B0 certified for all waves after the barrier (A0 auto-waited)
    SBAR();

    // ---- main loop: 16 regions ----
    body(aF0, aF1, 0, 1, true, 3, true);  VMCNT(6); SBAR();   // r0: certify B1
#pragma unroll
    for (int r = 1; r <= 12; ++r) {
        if (r & 1) body(aF1, aF0, r & 3, r + 1, true, r + 3, true);
        else       body(aF0, aF1, r & 3, r + 1, true, r + 3, true);
        VMCNT(6);      // certify B(r+1); {B(r+2), A(r+1)x4, B(r+3)} stay in flight
        SBAR();
    }
    body(aF1, aF0, 1, 14, true, 0, false); VMCNT(5); SBAR();  // r13: certify B14
    body(aF0, aF1, 2, 15, true, 0, false); VMCNT(4); SBAR();  // r14: certify B15
    body(aF1, aF0, 3, 0, false, 0, false);                    // r15

    // ---- x loads (post-loop; ride in regs until overlay is safe) ----
    float4 xv[5];
#pragma unroll
    for (int k = 0; k < 5; ++k) {
        int c = tid + k * 512;                   // < 2096 = 131 rows * 16 chunks
        float4 v = make_float4(0.f, 0.f, 0.f, 0.f);
        if (c < 2096) {
            int row = c >> 4, q = c & 15;
            int rg = t0 - 3 + row;
            if (rg >= 0 && (rg >> 12) == (t0 >> 12))   // zero across batch boundary
                v = *reinterpret_cast<const float4*>(&x[(size_t)rg * DD + d0 + q * 4]);
        }
        xv[k] = v;
    }
    __syncthreads();   // all K-loop LDS reads done; overlay X/Y

    float* smX = reinterpret_cast<float*>(lds);
#pragma unroll
    for (int k = 0; k < 5; ++k) {
        int c = tid + k * 512;
        if (c < 2096) {
            int row = c >> 4, q = c & 15;
            *reinterpret_cast<float4*>(&smX[row * XSTR2 + q * 4]) = xv[k];
        }
    }
    __syncthreads();

    // ---- epilogue: bias + conv taps (reg idx j) + silu -> smY ----
    float4 bb[4];
#pragma unroll
    for (int m = 0; m < 4; ++m)
        bb[m] = *reinterpret_cast<const float4*>(&b2[n0 + wm * 64 + m * 16 + hi * 4]);

    float* smY = reinterpret_cast<float*>(lds + 35632);
#pragma unroll
    for (int nr = 0; nr < 4; ++nr) {
        int tl = wn * 64 + nr * 16 + la;
#pragma unroll
        for (int m = 0; m < 4; ++m) {
            int dl = wm * 16 + m * 4 + hi;
            float pv =
                  (acc[m][nr][0] + bb[m].x) * smX[(tl + 0) * XSTR2 + dl]
                + (acc[m][nr][1] + bb[m].y) * smX[(tl + 1) * XSTR2 + dl]
                + (acc[m][nr][2] + bb[m].z) * smX[(tl + 2) * XSTR2 + dl]
                + (acc[m][nr][3] + bb[m].w) * smX[(tl + 3) * XSTR2 + dl];
            smY[tl * XSTR2 + dl] = pv / (1.0f + __expf(-pv));
        }
    }
    __syncthreads();

    // ---- coalesced store: 128 rows x 64 f32 (256 B per row) ----
    for (int c = tid; c < 128 * 16; c += 512) {
        int row = c >> 4, q = c & 15;
        float4 v = *reinterpret_cast<const float4*>(&smY[row * XSTR2 + q * 4]);
        *reinterpret_cast<float4*>(&out[(size_t)(t0 + row) * DD + d0 + q * 4]) = v;
    }
}

extern "C" void kernel_launch(void* const* d_in, const int* in_sizes, int n_in,
                              void* d_out, int out_size, void* d_ws, size_t ws_size,
                              hipStream_t stream) {
    const float* x   = (const float*)d_in[0];
    const float* gen = (const float*)d_in[1];
    const float* w1  = (const float*)d_in[2];
    const float* w2  = (const float*)d_in[3];
    const float* b2  = (const float*)d_in[4];
    float* out = (float*)d_out;

    char* ws = (char*)d_ws;
    size_t off = 0;
    unsigned short* gen_b = (unsigned short*)(ws + off); off += (size_t)BT * DMm * 2;
    unsigned short* w1_b  = (unsigned short*)(ws + off); off += (size_t)DGg * DMm * 2;
    unsigned short* w2_b  = (unsigned short*)(ws + off); off += (size_t)DW * DGg * 2;
    unsigned short* h_b   = (unsigned short*)(ws + off); off += (size_t)BT * DGg * 2;

    int total4 = NB1 + NB2 + NB3;
    cast_all_kernel<<<(total4 + 255) / 256, 256, 0, stream>>>(gen, w1, w2, gen_b);

    gemm1_silu_kernel<<<dim3(DGg / 128, BT / 128), 256, 0, stream>>>(gen_b, w1_b, h_b);
    gemm2_conv_silu_kernel<<<4096, 512, 0, stream>>>(h_b, w2_b, b2, x, out);
}

// Round 15
// 232.751 us; speedup vs baseline: 1.5260x; 1.5260x over previous
//
#include <hip/hip_runtime.h>
#include <hip/hip_bf16.h>
#include <stdint.h>

// Problem constants
#define TLEN 4096
#define DMm  2048
#define DD   4096
#define DGg  512
#define BT   8192          // B*T
#define DW   16384         // D*W

typedef __attribute__((ext_vector_type(8))) short bf16x8;
typedef __attribute__((ext_vector_type(4))) float f32x4;

__device__ __forceinline__ unsigned short f2bf(float f) {
    union { float f; unsigned u; } c; c.f = f;
    unsigned u = c.u;
    unsigned r = (u + 0x7FFFu + ((u >> 16) & 1u)) >> 16;   // RNE
    return (unsigned short)r;
}

// ---------------- fused cast f32 -> bf16 for gen|w1|w2 (contiguous in ws) ----
#define NB1 (BT * DMm / 4)
#define NB2 (DGg * DMm / 4)
#define NB3 (DW * DGg / 4)
__global__ void cast_all_kernel(const float* __restrict__ g,
                                const float* __restrict__ w1,
                                const float* __restrict__ w2,
                                unsigned short* __restrict__ o) {
    int i = blockIdx.x * blockDim.x + threadIdx.x;
    if (i >= NB1 + NB2 + NB3) return;
    const float* src; int j = i;
    if (j < NB1) { src = g; }
    else if (j < NB1 + NB2) { src = w1; j -= NB1; }
    else { src = w2; j -= NB1 + NB2; }
    float4 v = reinterpret_cast<const float4*>(src)[j];
    ushort4 u;
    u.x = f2bf(v.x); u.y = f2bf(v.y); u.z = f2bf(v.z); u.w = f2bf(v.w);
    reinterpret_cast<ushort4*>(o)[i] = u;
}

#define GLDS16(gp, lp)                                                         \
    __builtin_amdgcn_global_load_lds(                                          \
        (__attribute__((address_space(1))) const void*)(gp),                   \
        (__attribute__((address_space(3))) void*)(lp), 16, 0, 0)

#define VMCNT(n) asm volatile("s_waitcnt vmcnt(" #n ")" ::: "memory")
#define SBAR()   __builtin_amdgcn_s_barrier()
#define SCHED0() __builtin_amdgcn_sched_barrier(0)

// ===== GEMM1: h = silu(gen @ w1^T) -> H bf16 [BT][DG], r13-style pipeline =====
// D[g][t] = sum_k W1b[g][k] * Gen_b[t][k]; block tile 64g x 128t; K=2048 ->
// 64 tiles BK=32, ring-3.  512 blocks x 256 thr (4 waves, 2g x 2t; wave
// 32g x 64t, acc[2][4]=32 VGPR) -> 2 blocks/CU = 2 independent barrier
// domains (m114 overlap).  XOR slot swizzle on both stage-source and read.
// Ledger (3 loads/thread/tile: A1+B2): prologue tiles 0,1 -> VMCNT(3)
// certifies 0; region r (0..61) stages r+2 into par (r+2)%3 (== r-1, readers
// certified by its barrier) -> VMCNT(3) certifies r+1; r=62 VMCNT(0); 63 bare.
// LDS: A[3][64 rows][64B] @0 (12K), B[3][128 rows][64B] @12288 (24K) = 36KB;
// epilogue overlay smY bf16 [128][72] @0 (18.4KB).
#define G1_B 12288

__global__ __launch_bounds__(256, 2) void gemm1_silu_kernel(
    const unsigned short* __restrict__ Gen_b,
    const unsigned short* __restrict__ W1b,
    unsigned short* __restrict__ H)
{
    __shared__ __attribute__((aligned(16))) char lds[36864];
    const int tid  = threadIdx.x;
    const int lane = tid & 63, wave = tid >> 6;
    const int wm   = wave >> 1, wn = wave & 1;
    const int la   = lane & 15, hi = lane >> 4;

    // XCD swizzle (512 blocks, %8==0 -> bijective); g fast within XCD so
    // consecutive blocks share the gen t-tile (L2 reuse).
    int bid = blockIdx.x;
    int swz = (bid & 7) * 64 + (bid >> 3);
    const int g0 = (swz & 7) * 64;     // 8 g-tiles
    const int t0 = (swz >> 3) * 128;   // 64 t-tiles

    const int srow = lane >> 2;                               // 0..15
    const int scol = ((lane & 3) ^ ((srow >> 1) & 3)) * 8;    // pre-swizzled src col

    auto stageA = [&](int tk, int p) {   // 1 load/thread: 4KB tile (64 rows)
        int row = wave * 16 + srow;                           // 0..63
        GLDS16(W1b + (size_t)(g0 + row) * DMm + tk * 32 + scol,
               lds + p * 4096 + wave * 1024);
    };
    auto stageB = [&](int tk, int p) {   // 2 loads/thread: 8KB tile (128 rows)
#pragma unroll
        for (int q = 0; q < 2; ++q) {
            int chunk = wave * 2 + q, row = chunk * 16 + srow;  // 0..127
            GLDS16(Gen_b + (size_t)(t0 + row) * DMm + tk * 32 + scol,
                   lds + G1_B + p * 8192 + chunk * 1024);
        }
    };

    f32x4 acc[2][4] = {};
    const int slotb = (hi ^ ((la >> 1) & 3)) * 16;   // swizzled 16B slot
    const int aOff  = (wm * 32 + la) * 64 + slotb;
    const int bOff  = G1_B + (wn * 64 + la) * 64 + slotb;

    auto region = [&](int r, bool doStage) {
        const int p = r % 3;
        const char* aB = lds + p * 4096 + aOff;
        const char* bB = lds + p * 8192 + bOff;
        bf16x8 aF[2], bF[4];
#pragma unroll
        for (int m = 0; m < 2; ++m)
            aF[m] = *reinterpret_cast<const bf16x8*>(aB + m * 1024);
#pragma unroll
        for (int nr = 0; nr < 4; ++nr)
            bF[nr] = *reinterpret_cast<const bf16x8*>(bB + nr * 1024);
        if (doStage) { stageA(r + 2, (r + 2) % 3); stageB(r + 2, (r + 2) % 3); }
        SCHED0();
        __builtin_amdgcn_s_setprio(1);
#pragma unroll
        for (int m = 0; m < 2; ++m)
#pragma unroll
            for (int nr = 0; nr < 4; ++nr)
                acc[m][nr] = __builtin_amdgcn_mfma_f32_16x16x32_bf16(
                    aF[m], bF[nr], acc[m][nr], 0, 0, 0);
        __builtin_amdgcn_s_setprio(0);
        SCHED0();
    };

    // ---- prologue: stage tiles 0,1 ----
    stageA(0, 0); stageB(0, 0);
    stageA(1, 1); stageB(1, 1);
    VMCNT(3);
    SBAR();

    // ---- main loop: 64 regions ----
    for (int r = 0; r < 62; ++r) {
        region(r, true);
        VMCNT(3);      // certify tile r+1; tile r+2 (3 loads) in flight
        SBAR();
    }
    region(62, false); VMCNT(0); SBAR();   // certify tile 63
    region(63, false);

    __syncthreads();   // all K-loop LDS reads done; overlay smY

    // ---- epilogue: silu -> bf16 -> smY [128t][stride 72] -> coalesced store ----
    unsigned short* smY = reinterpret_cast<unsigned short*>(lds);
#pragma unroll
    for (int nr = 0; nr < 4; ++nr) {
        int tl = wn * 64 + nr * 16 + la;
#pragma unroll
        for (int m = 0; m < 2; ++m) {
            int gl0 = wm * 32 + m * 16 + hi * 4;
#pragma unroll
            for (int j = 0; j < 4; ++j) {
                float v = acc[m][nr][j];
                smY[tl * 72 + gl0 + j] = f2bf(v / (1.0f + __expf(-v)));
            }
        }
    }
    __syncthreads();

    for (int c = tid; c < 128 * 8; c += 256) {
        int row = c >> 3, q = c & 7;
        bf16x8 v = *reinterpret_cast<const bf16x8*>(&smY[row * 72 + q * 8]);
        *reinterpret_cast<bf16x8*>(&H[(size_t)(t0 + row) * DGg + g0 + q * 8]) = v;
    }
}

// ===== GEMM2 fused: 256n x 128t, 8 waves (64x64), ring-3 BK=32, 2 blk/CU =====
// (round-13 kernel, verbatim — 179us, ~84% of its LDS-pipe structural bound)
#define LDS_B2 49152

__global__ __launch_bounds__(512, 4) void gemm2_conv_silu_kernel(
    const unsigned short* __restrict__ Hb,
    const unsigned short* __restrict__ W2b,
    const float* __restrict__ b2,
    const float* __restrict__ x,
    float* __restrict__ out)
{
    __shared__ __attribute__((aligned(16))) char lds[73728];
    const int tid  = threadIdx.x;
    const int lane = tid & 63, wave = tid >> 6;
    const int wm   = wave >> 1, wn = wave & 1;
    const int la   = lane & 15, hi = lane >> 4;

    // XCD-aware swizzle (4096 blocks, %8==0 -> bijective); t fast within XCD
    int bid = blockIdx.x;
    int swz = (bid & 7) * 512 + (bid >> 3);
    const int n0 = (swz >> 6) * 256;   // 64 n-tiles
    const int t0 = (swz & 63) * 128;   // 64 t-tiles
    const int d0 = n0 >> 2;

    const int srow = lane >> 2;                               // 0..15
    const int scol = ((lane & 3) ^ ((srow >> 1) & 3)) * 8;    // pre-swizzled src col

    auto stageA = [&](int tk, int p) {   // 2 loads/thread: 16KB tile (256 rows)
#pragma unroll
        for (int q = 0; q < 2; ++q) {
            int chunk = wave * 2 + q, row = chunk * 16 + srow;   // 0..255
            GLDS16(W2b + (size_t)(n0 + row) * DGg + tk * 32 + scol,
                   lds + p * 16384 + chunk * 1024);
        }
    };
    auto stageB = [&](int tk, int p) {   // 1 load/thread: 8KB tile (128 rows)
        int row = wave * 16 + srow;                              // 0..127
        GLDS16(Hb + (size_t)(t0 + row) * DGg + tk * 32 + scol,
               lds + LDS_B2 + p * 8192 + wave * 1024);
    };

    f32x4 acc[4][4] = {};
    const int slotb = (hi ^ ((la >> 1) & 3)) * 16;   // swizzled 16B slot
    const int aOff  = (wm * 64 + la) * 64 + slotb;
    const int bOff  = LDS_B2 + (wn * 64 + la) * 64 + slotb;

    auto region = [&](int r, bool doStage) {
        const int p = r % 3;
        const char* aB = lds + p * 16384 + aOff;
        const char* bB = lds + p * 8192 + bOff;
        bf16x8 aF[4], bF[4];
#pragma unroll
        for (int m = 0; m < 4; ++m)
            aF[m] = *reinterpret_cast<const bf16x8*>(aB + m * 1024);
#pragma unroll
        for (int nr = 0; nr < 4; ++nr)
            bF[nr] = *reinterpret_cast<const bf16x8*>(bB + nr * 1024);
        if (doStage) { stageA(r + 2, (r + 2) % 3); stageB(r + 2, (r + 2) % 3); }
        SCHED0();   // pin reads+stage above the MFMA cluster
        __builtin_amdgcn_s_setprio(1);
#pragma unroll
        for (int m = 0; m < 4; ++m)
#pragma unroll
            for (int nr = 0; nr < 4; ++nr)
                acc[m][nr] = __builtin_amdgcn_mfma_f32_16x16x32_bf16(
                    aF[m], bF[nr], acc[m][nr], 0, 0, 0);
        __builtin_amdgcn_s_setprio(0);
        SCHED0();
    };

    // ---- prologue: stage tiles 0,1 ----
    stageA(0, 0); stageB(0, 0);
    stageA(1, 1); stageB(1, 1);
    VMCNT(3);     // tile 0 certified for all waves after the barrier
    SBAR();

    // ---- main loop: 16 regions, counted vmcnt BEFORE each barrier ----
#pragma unroll
    for (int r = 0; r < 14; ++r) {
        region(r, true);
        VMCNT(3);      // certify tile r+1; tile r+2 (3 loads) in flight
        SBAR();
    }
    region(14, false); VMCNT(0); SBAR();   // certify tile 15
    region(15, false);

    // ---- x loads (post-loop; ride in regs until overlay is safe) ----
    float4 xv[5];
#pragma unroll
    for (int k = 0; k < 5; ++k) {
        int c = tid + k * 512;                   // < 2096 = 131 rows * 16 chunks
        float4 v = make_float4(0.f, 0.f, 0.f, 0.f);
        if (c < 2096) {
            int row = c >> 4, q = c & 15;
            int rg = t0 - 3 + row;
            if (rg >= 0 && (rg >> 12) == (t0 >> 12))   // zero across batch boundary
                v = *reinterpret_cast<const float4*>(&x[(size_t)rg * DD + d0 + q * 4]);
        }
        xv[k] = v;
    }
    __syncthreads();   // all K-loop LDS reads done; overlay X/Y

    float* smX = reinterpret_cast<float*>(lds);
#pragma unroll
    for (int k = 0; k < 5; ++k) {
        int c = tid + k * 512;
        if (c < 2096) {
            int row = c >> 4, q = c & 15;
            *reinterpret_cast<float4*>(&smX[row * 68 + q * 4]) = xv[k];
        }
    }
    __syncthreads();

    // ---- epilogue: bias + conv taps (reg idx j) + silu -> smY ----
    float4 bb[4];
#pragma unroll
    for (int m = 0; m < 4; ++m)
        bb[m] = *reinterpret_cast<const float4*>(&b2[n0 + wm * 64 + m * 16 + hi * 4]);

    float* smY = reinterpret_cast<float*>(lds + 35632);
#pragma unroll
    for (int nr = 0; nr < 4; ++nr) {
        int tl = wn * 64 + nr * 16 + la;
#pragma unroll
        for (int m = 0; m < 4; ++m) {
            int dl = wm * 16 + m * 4 + hi;
            float pv =
                  (acc[m][nr][0] + bb[m].x) * smX[(tl + 0) * 68 + dl]
                + (acc[m][nr][1] + bb[m].y) * smX[(tl + 1) * 68 + dl]
                + (acc[m][nr][2] + bb[m].z) * smX[(tl + 2) * 68 + dl]
                + (acc[m][nr][3] + bb[m].w) * smX[(tl + 3) * 68 + dl];
            smY[tl * 68 + dl] = pv / (1.0f + __expf(-pv));
        }
    }
    __syncthreads();

    // ---- coalesced store: 128 rows x 64 f32 (256 B per row) ----
    for (int c = tid; c < 128 * 16; c += 512) {
        int row = c >> 4, q = c & 15;
        float4 v = *reinterpret_cast<const float4*>(&smY[row * 68 + q * 4]);
        *reinterpret_cast<float4*>(&out[(size_t)(t0 + row) * DD + d0 + q * 4]) = v;
    }
}

extern "C" void kernel_launch(void* const* d_in, const int* in_sizes, int n_in,
                              void* d_out, int out_size, void* d_ws, size_t ws_size,
                              hipStream_t stream) {
    const float* x   = (const float*)d_in[0];
    const float* gen = (const float*)d_in[1];
    const float* w1  = (const float*)d_in[2];
    const float* w2  = (const float*)d_in[3];
    const float* b2  = (const float*)d_in[4];
    float* out = (float*)d_out;

    char* ws = (char*)d_ws;
    size_t off = 0;
    unsigned short* gen_b = (unsigned short*)(ws + off); off += (size_t)BT * DMm * 2;
    unsigned short* w1_b  = (unsigned short*)(ws + off); off += (size_t)DGg * DMm * 2;
    unsigned short* w2_b  = (unsigned short*)(ws + off); off += (size_t)DW * DGg * 2;
    unsigned short* h_b   = (unsigned short*)(ws + off); off += (size_t)BT * DGg * 2;

    int total4 = NB1 + NB2 + NB3;
    cast_all_kernel<<<(total4 + 255) / 256, 256, 0, stream>>>(gen, w1, w2, gen_b);

    gemm1_silu_kernel<<<512, 256, 0, stream>>>(gen_b, w1_b, h_b);
    gemm2_conv_silu_kernel<<<4096, 512, 0, stream>>>(h_b, w2_b, b2, x, out);
}